// Round 2
// baseline (1720.856 us; speedup 1.0000x reference)
//
#include <hip/hip_runtime.h>
#include <cstdint>
#include <cstddef>

// GTM forward: out[0] = -ll, out[1..] = R^T [N=131072][K=360]
//   E'_k(n) = b*(Y_k . t_n - 0.5*||Y_k||^2)   (||t||^2 shift cancels in softmax AND in log s)
//   R[:,n] = softmax_k(E'), ll_n = 256*log(b/2pi) + log(sum exp(E'-max)) - log 360
// GEMM via bf16 hi/lo split (3 MFMA passes) for fp32-grade accuracy on E.

#define KNODES 360
#define MPAD   384
#define MRBF   145
#define DD     512
#define NTOT   131072
#define BN     64
#define NBLK   (NTOT / BN)    // 2048
#define NKS    (DD / 32)      // 16 K-steps of 32
#define CHUNKB (MPAD * 32 * 2) // 24576 bytes: one K-chunk of A in bf16

typedef float  f32x4  __attribute__((ext_vector_type(4)));
typedef short  s16x8  __attribute__((ext_vector_type(8)));
typedef __bf16 bf16x8 __attribute__((ext_vector_type(8)));

static __device__ __forceinline__ bf16x8 as_bf(s16x8 v) { return __builtin_bit_cast(bf16x8, v); }

// round-to-nearest-even fp32 -> bf16 (data has no NaN/Inf)
static __device__ __forceinline__ unsigned short f2bf(float x) {
  unsigned u = __float_as_uint(x);
  u += 0x7FFFu + ((u >> 16) & 1u);
  return (unsigned short)(u >> 16);
}
static __device__ __forceinline__ float bf2f(unsigned short h) {
  return __uint_as_float(((unsigned)h) << 16);
}

// async global->LDS, 16B per lane; LDS dest = wave-uniform base + lane*16
static __device__ __forceinline__ void gload16(const void* g, const char* l) {
  __builtin_amdgcn_global_load_lds(
      (const __attribute__((address_space(1))) void*)g,
      (__attribute__((address_space(3))) void*)l,
      16, 0, 0);
}

// ---------------------------------------------------------------------------
// prep: phi (analytic, sigma = 1/6 exactly), Y = phi@W, c = 0.5*||Y_k||^2,
// store Y hi/lo bf16 pre-swizzled in per-32k chunks. Rows 360..383: Y=0, c=1e30.
// ---------------------------------------------------------------------------
__global__ __launch_bounds__(128) void k_prep(const float* __restrict__ W,
                                              unsigned short* __restrict__ ahi,
                                              unsigned short* __restrict__ alo,
                                              float* __restrict__ cbuf,
                                              float* __restrict__ llbuf) {
  const int k   = blockIdx.x;    // latent row 0..383
  const int tid = threadIdx.x;   // 0..127
  if (k == 0 && tid == 0) llbuf[0] = 0.0f;

  __shared__ float phi[MRBF];
  __shared__ float red[128];

  if (k < KNODES) {
    for (int m = tid; m < MRBF; m += 128) {
      float p = 1.0f;                      // bias column (m == 144)
      if (m < MRBF - 1) {
        const float ca = -11.0f / 12.0f + (1.0f / 6.0f) * (float)(m / 12);
        const float cb = -11.0f / 12.0f + (1.0f / 6.0f) * (float)(m % 12);
        const float xa = -1.0f + (2.0f / 19.0f) * (float)(k / 18);
        const float xb = -1.0f + (2.0f / 17.0f) * (float)(k % 18);
        const float dx = xa - ca, dy = xb - cb;
        p = expf(-3.0f * (dx * dx + dy * dy));   // exp(-d2/(2*sigma)), sigma=1/6
      }
      phi[m] = p;
    }
  }
  __syncthreads();

  float ysq = 0.0f;
  #pragma unroll
  for (int q = 0; q < 4; ++q) {
    const int d = tid + 128 * q;
    float y = 0.0f;
    if (k < KNODES) {
      for (int m = 0; m < MRBF; ++m) y = fmaf(phi[m], W[m * DD + d], y);
    }
    ysq += y * y;
    const unsigned short h = f2bf(y);
    const unsigned short l = f2bf(y - bf2f(h));
    // swizzled byte offset inside chunk (d>>5): (row*64 + (d&31)*2) ^ ((row&7)<<4)
    const int idx = ((d >> 5) * CHUNKB + ((k * 64 + (d & 31) * 2) ^ ((k & 7) << 4))) >> 1;
    ahi[idx] = h;
    alo[idx] = l;
  }

  red[tid] = ysq;
  __syncthreads();
  #pragma unroll
  for (int s = 64; s > 0; s >>= 1) {
    if (tid < s) red[tid] += red[tid + s];
    __syncthreads();
  }
  if (tid == 0) cbuf[k] = (k < KNODES) ? 0.5f * red[0] : 1.0e30f;
}

// ---------------------------------------------------------------------------
// main: per block = all 384 rows x 64 columns; bf16x3 MFMA + fused softmax
// ---------------------------------------------------------------------------
#define LDS_AHI 0
#define LDS_ALO 24576
#define LDS_BHI 49152
#define LDS_BLO 53248
#define LDS_RED 57344
#define LDS_TOT 59392

__global__ __launch_bounds__(256, 2) void k_main(const float* __restrict__ t,
                                                 const float* __restrict__ beta,
                                                 const unsigned short* __restrict__ ahi,
                                                 const unsigned short* __restrict__ alo,
                                                 const float* __restrict__ cbuf,
                                                 float* __restrict__ out,
                                                 float* __restrict__ llbuf) {
  __shared__ __align__(16) char smem[LDS_TOT];
  const int tid  = threadIdx.x;
  const int lane = tid & 63;
  const int wv   = tid >> 6;     // wave 0..3 -> rows [wv*96, wv*96+96)
  const int col  = lane & 15;
  const int kg   = lane >> 4;    // k-group for fragments
  const int n0   = blockIdx.x * BN;
  const float b  = beta[0];

  f32x4 acc[6][4] = {};          // [m-frag][n-frag], rows = wv*96+i*16+kg*4+r, col = j*16+col

  const float* tsrc = t + (size_t)(n0 + (tid >> 2)) * DD + (tid & 3) * 8;
  const int brow  = tid >> 2;
  const int bbyte = ((brow * 64 + (tid & 3) * 16) ^ ((brow & 7) << 4));

  for (int ks = 0; ks < NKS; ++ks) {
    __syncthreads();
    // ---- stage A (pre-swizzled bf16 hi/lo) via global_load_lds, 16B/lane x 6
    #pragma unroll
    for (int is = 0; is < 6; ++is) {
      gload16((const char*)ahi + ks * CHUNKB + is * 4096 + tid * 16,
              smem + LDS_AHI + is * 4096 + wv * 1024);
      gload16((const char*)alo + ks * CHUNKB + is * 4096 + tid * 16,
              smem + LDS_ALO + is * 4096 + wv * 1024);
    }
    // ---- stage B: 8 floats of t -> bf16 hi/lo, swizzled ds_write
    {
      const float4 v0 = *(const float4*)(tsrc + ks * 32);
      const float4 v1 = *(const float4*)(tsrc + ks * 32 + 4);
      const float f[8] = {v0.x, v0.y, v0.z, v0.w, v1.x, v1.y, v1.z, v1.w};
      s16x8 hv, lv;
      #pragma unroll
      for (int q = 0; q < 8; ++q) {
        const unsigned short h = f2bf(f[q]);
        hv[q] = (short)h;
        lv[q] = (short)f2bf(f[q] - bf2f(h));
      }
      *(s16x8*)(smem + LDS_BHI + bbyte) = hv;
      *(s16x8*)(smem + LDS_BLO + bbyte) = lv;
    }
    __syncthreads();
    // ---- fragments + 3-pass MFMA (hi*hi + hi*lo + lo*hi)
    s16x8 Bh[4], Bl[4];
    #pragma unroll
    for (int j = 0; j < 4; ++j) {
      const int nn  = j * 16 + col;
      const int byo = ((nn * 64 + kg * 16) ^ ((nn & 7) << 4));
      Bh[j] = *(const s16x8*)(smem + LDS_BHI + byo);
      Bl[j] = *(const s16x8*)(smem + LDS_BLO + byo);
    }
    #pragma unroll
    for (int i = 0; i < 6; ++i) {
      const int m   = wv * 96 + i * 16 + col;
      const int byo = ((m * 64 + kg * 16) ^ ((m & 7) << 4));
      const s16x8 Ah = *(const s16x8*)(smem + LDS_AHI + byo);
      const s16x8 Al = *(const s16x8*)(smem + LDS_ALO + byo);
      #pragma unroll
      for (int j = 0; j < 4; ++j) {
        acc[i][j] = __builtin_amdgcn_mfma_f32_16x16x32_bf16(as_bf(Ah), as_bf(Bh[j]), acc[i][j], 0, 0, 0);
        acc[i][j] = __builtin_amdgcn_mfma_f32_16x16x32_bf16(as_bf(Ah), as_bf(Bl[j]), acc[i][j], 0, 0, 0);
        acc[i][j] = __builtin_amdgcn_mfma_f32_16x16x32_bf16(as_bf(Al), as_bf(Bh[j]), acc[i][j], 0, 0, 0);
      }
    }
  }

  // ---- epilogue: E = b*(dot - c[m]); column softmax over 384 rows; R^T out
  float* red  = (float*)(smem + LDS_RED);   // [4 waves][64 cols]
  float* red2 = red + 256;

  f32x4 c4[6];
  #pragma unroll
  for (int i = 0; i < 6; ++i)
    c4[i] = *(const f32x4*)(cbuf + wv * 96 + i * 16 + kg * 4);

  float colmax[4] = {-3.0e38f, -3.0e38f, -3.0e38f, -3.0e38f};
  #pragma unroll
  for (int i = 0; i < 6; ++i) {
    #pragma unroll
    for (int j = 0; j < 4; ++j) {
      acc[i][j] = (acc[i][j] - c4[i]) * b;   // padded rows: c=1e30 -> E ~ -1e30
      #pragma unroll
      for (int r = 0; r < 4; ++r) colmax[j] = fmaxf(colmax[j], acc[i][j][r]);
    }
  }
  #pragma unroll
  for (int j = 0; j < 4; ++j) {
    colmax[j] = fmaxf(colmax[j], __shfl_xor(colmax[j], 16));
    colmax[j] = fmaxf(colmax[j], __shfl_xor(colmax[j], 32));
  }
  if (lane < 16) {
    #pragma unroll
    for (int j = 0; j < 4; ++j) red[wv * 64 + j * 16 + lane] = colmax[j];
  }
  __syncthreads();

  float fullmax[4];
  float colsum[4] = {0.0f, 0.0f, 0.0f, 0.0f};
  #pragma unroll
  for (int j = 0; j < 4; ++j) {
    const int cc = j * 16 + col;
    fullmax[j] = fmaxf(fmaxf(red[cc], red[64 + cc]), fmaxf(red[128 + cc], red[192 + cc]));
  }
  #pragma unroll
  for (int i = 0; i < 6; ++i) {
    #pragma unroll
    for (int j = 0; j < 4; ++j) {
      #pragma unroll
      for (int r = 0; r < 4; ++r) {
        const float p = expf(acc[i][j][r] - fullmax[j]);  // pad rows -> exp(-huge) = 0
        acc[i][j][r] = p;
        colsum[j] += p;
      }
    }
  }
  #pragma unroll
  for (int j = 0; j < 4; ++j) {
    colsum[j] += __shfl_xor(colsum[j], 16);
    colsum[j] += __shfl_xor(colsum[j], 32);
  }
  if (lane < 16) {
    #pragma unroll
    for (int j = 0; j < 4; ++j) red2[wv * 64 + j * 16 + lane] = colsum[j];
  }
  __syncthreads();

  float s[4];
  #pragma unroll
  for (int j = 0; j < 4; ++j) {
    const int cc = j * 16 + col;
    s[j] = (red2[cc] + red2[64 + cc]) + (red2[128 + cc] + red2[192 + cc]);
  }

  // log-likelihood partial: wave 0, lanes 0..15 cover all 64 columns once
  float llp = 0.0f;
  if (lane < 16) {
    #pragma unroll
    for (int j = 0; j < 4; ++j) llp += logf(s[j]);
  }
  if (wv == 0) {
    #pragma unroll
    for (int mk = 1; mk < 64; mk <<= 1) llp += __shfl_xor(llp, mk);
    if (lane == 0) atomicAdd(llbuf, llp);
  }

  float inv[4];
  #pragma unroll
  for (int j = 0; j < 4; ++j) inv[j] = 1.0f / s[j];
  #pragma unroll
  for (int i = 0; i < 6; ++i) {
    #pragma unroll
    for (int j = 0; j < 4; ++j) acc[i][j] *= inv[j];
  }

  // ---- transpose via LDS (stride 18: write-conflict-free, reads 4-way) ----
  float* Rt = (float*)smem;  // [384][18] floats = 27648 B, overlays dead A region
  #pragma unroll 1
  for (int jj = 0; jj < 4; ++jj) {
    __syncthreads();
    #pragma unroll
    for (int i = 0; i < 6; ++i) {
      const int mbase = wv * 96 + i * 16 + kg * 4;
      #pragma unroll
      for (int r = 0; r < 4; ++r) Rt[(mbase + r) * 18 + col] = acc[i][jj][r];
    }
    __syncthreads();
    #pragma unroll
    for (int c2l = 0; c2l < 4; ++c2l) {
      const int cc = wv * 4 + c2l;
      const size_t n = (size_t)(n0 + jj * 16 + cc);
      #pragma unroll
      for (int i2 = 0; i2 < 6; ++i2) {
        const int m = lane + 64 * i2;
        if (m < KNODES) out[1 + n * KNODES + m] = Rt[m * 18 + cc];
      }
    }
  }
}

// ---------------------------------------------------------------------------
__global__ void k_fin(const float* __restrict__ beta, const float* __restrict__ llbuf,
                      float* __restrict__ out) {
  const float b = beta[0];
  // -ll = -(256*log(b/2pi) - log(360) + (1/N)*sum log s)
  out[0] = -(256.0f * logf(b * (1.0f / 6.283185307179586f)) - logf(360.0f)
             + llbuf[0] * (1.0f / 131072.0f));
}

extern "C" void kernel_launch(void* const* d_in, const int* in_sizes, int n_in,
                              void* d_out, int out_size, void* d_ws, size_t ws_size,
                              hipStream_t stream) {
  const float* t    = (const float*)d_in[0];
  const float* W    = (const float*)d_in[1];
  const float* beta = (const float*)d_in[2];
  float* out = (float*)d_out;

  // ws layout: A_hi[393216 B] | A_lo[393216 B] | c[1536 B] | ll[4 B]  (~788 KB)
  unsigned short* ahi = (unsigned short*)d_ws;
  unsigned short* alo = (unsigned short*)((char*)d_ws + 393216);
  float* cbuf  = (float*)((char*)d_ws + 786432);
  float* llbuf = (float*)((char*)d_ws + 787968);

  hipLaunchKernelGGL(k_prep, dim3(MPAD), dim3(128), 0, stream, W, ahi, alo, cbuf, llbuf);
  hipLaunchKernelGGL(k_main, dim3(NBLK), dim3(256), 0, stream,
                     t, beta, ahi, alo, cbuf, out, llbuf);
  hipLaunchKernelGGL(k_fin, dim3(1), dim3(1), 0, stream, beta, llbuf, out);
}

// Round 3
// 564.019 us; speedup vs baseline: 3.0511x; 3.0511x over previous
//
#include <hip/hip_runtime.h>
#include <cstdint>
#include <cstddef>

// GTM forward: out[0] = -ll, out[1..] = R^T [N=131072][K=360]
//   E'_k(n) = b*(Y_k . t_n - 0.5*||Y_k||^2)   (||t||^2 shift cancels in softmax AND in log s)
//   R[:,n] = softmax_k(E'), ll_n = 256*log(b/2pi) + log(sum exp(E'-max)) - log 360
// GEMM via bf16 hi/lo split (3 MFMA passes) for fp32-grade accuracy on E.
//
// R2 fix: transpose loop over jj was `#pragma unroll 1` -> acc[i][jj] runtime-
// indexed -> entire accumulator spilled to scratch (rule #20): 3.2 GB of
// scratch writes, WRITE_SIZE 4 GB, VGPR_Count 108. Full unroll keeps acc in
// registers; every acc access below is compile-time-constant indexed.

#define KNODES 360
#define MPAD   384
#define MRBF   145
#define DD     512
#define NTOT   131072
#define BN     64
#define NBLK   (NTOT / BN)    // 2048
#define NKS    (DD / 32)      // 16 K-steps of 32
#define CHUNKB (MPAD * 32 * 2) // 24576 bytes: one K-chunk of A in bf16

typedef float  f32x4  __attribute__((ext_vector_type(4)));
typedef short  s16x8  __attribute__((ext_vector_type(8)));
typedef __bf16 bf16x8 __attribute__((ext_vector_type(8)));

static __device__ __forceinline__ bf16x8 as_bf(s16x8 v) { return __builtin_bit_cast(bf16x8, v); }

// round-to-nearest-even fp32 -> bf16 (data has no NaN/Inf)
static __device__ __forceinline__ unsigned short f2bf(float x) {
  unsigned u = __float_as_uint(x);
  u += 0x7FFFu + ((u >> 16) & 1u);
  return (unsigned short)(u >> 16);
}
static __device__ __forceinline__ float bf2f(unsigned short h) {
  return __uint_as_float(((unsigned)h) << 16);
}

// async global->LDS, 16B per lane; LDS dest = wave-uniform base + lane*16
static __device__ __forceinline__ void gload16(const void* g, const char* l) {
  __builtin_amdgcn_global_load_lds(
      (const __attribute__((address_space(1))) void*)g,
      (__attribute__((address_space(3))) void*)l,
      16, 0, 0);
}

// ---------------------------------------------------------------------------
// prep: phi (analytic, sigma = 1/6 exactly), Y = phi@W, c = 0.5*||Y_k||^2,
// store Y hi/lo bf16 pre-swizzled in per-32k chunks. Rows 360..383: Y=0, c=1e30.
// ---------------------------------------------------------------------------
__global__ __launch_bounds__(128) void k_prep(const float* __restrict__ W,
                                              unsigned short* __restrict__ ahi,
                                              unsigned short* __restrict__ alo,
                                              float* __restrict__ cbuf,
                                              float* __restrict__ llbuf) {
  const int k   = blockIdx.x;    // latent row 0..383
  const int tid = threadIdx.x;   // 0..127
  if (k == 0 && tid == 0) llbuf[0] = 0.0f;

  __shared__ float phi[MRBF];
  __shared__ float red[128];

  if (k < KNODES) {
    for (int m = tid; m < MRBF; m += 128) {
      float p = 1.0f;                      // bias column (m == 144)
      if (m < MRBF - 1) {
        const float ca = -11.0f / 12.0f + (1.0f / 6.0f) * (float)(m / 12);
        const float cb = -11.0f / 12.0f + (1.0f / 6.0f) * (float)(m % 12);
        const float xa = -1.0f + (2.0f / 19.0f) * (float)(k / 18);
        const float xb = -1.0f + (2.0f / 17.0f) * (float)(k % 18);
        const float dx = xa - ca, dy = xb - cb;
        p = expf(-3.0f * (dx * dx + dy * dy));   // exp(-d2/(2*sigma)), sigma=1/6
      }
      phi[m] = p;
    }
  }
  __syncthreads();

  float ysq = 0.0f;
  #pragma unroll
  for (int q = 0; q < 4; ++q) {
    const int d = tid + 128 * q;
    float y = 0.0f;
    if (k < KNODES) {
      for (int m = 0; m < MRBF; ++m) y = fmaf(phi[m], W[m * DD + d], y);
    }
    ysq += y * y;
    const unsigned short h = f2bf(y);
    const unsigned short l = f2bf(y - bf2f(h));
    // swizzled byte offset inside chunk (d>>5): (row*64 + (d&31)*2) ^ ((row&7)<<4)
    const int idx = ((d >> 5) * CHUNKB + ((k * 64 + (d & 31) * 2) ^ ((k & 7) << 4))) >> 1;
    ahi[idx] = h;
    alo[idx] = l;
  }

  red[tid] = ysq;
  __syncthreads();
  #pragma unroll
  for (int s = 64; s > 0; s >>= 1) {
    if (tid < s) red[tid] += red[tid + s];
    __syncthreads();
  }
  if (tid == 0) cbuf[k] = (k < KNODES) ? 0.5f * red[0] : 1.0e30f;
}

// ---------------------------------------------------------------------------
// main: per block = all 384 rows x 64 columns; bf16x3 MFMA + fused softmax
// ---------------------------------------------------------------------------
#define LDS_AHI 0
#define LDS_ALO 24576
#define LDS_BHI 49152
#define LDS_BLO 53248
#define LDS_RED 57344
#define LDS_TOT 59392

__global__ __launch_bounds__(256, 2) void k_main(const float* __restrict__ t,
                                                 const float* __restrict__ beta,
                                                 const unsigned short* __restrict__ ahi,
                                                 const unsigned short* __restrict__ alo,
                                                 const float* __restrict__ cbuf,
                                                 float* __restrict__ out,
                                                 float* __restrict__ llbuf) {
  __shared__ __align__(16) char smem[LDS_TOT];
  const int tid  = threadIdx.x;
  const int lane = tid & 63;
  const int wv   = tid >> 6;     // wave 0..3 -> rows [wv*96, wv*96+96)
  const int col  = lane & 15;
  const int kg   = lane >> 4;    // k-group for fragments
  const int n0   = blockIdx.x * BN;
  const float b  = beta[0];

  f32x4 acc[6][4] = {};          // [m-frag][n-frag], rows = wv*96+i*16+kg*4+r, col = j*16+col

  const float* tsrc = t + (size_t)(n0 + (tid >> 2)) * DD + (tid & 3) * 8;
  const int brow  = tid >> 2;
  const int bbyte = ((brow * 64 + (tid & 3) * 16) ^ ((brow & 7) << 4));

  for (int ks = 0; ks < NKS; ++ks) {
    __syncthreads();
    // ---- stage A (pre-swizzled bf16 hi/lo) via global_load_lds, 16B/lane x 6
    #pragma unroll
    for (int is = 0; is < 6; ++is) {
      gload16((const char*)ahi + ks * CHUNKB + is * 4096 + tid * 16,
              smem + LDS_AHI + is * 4096 + wv * 1024);
      gload16((const char*)alo + ks * CHUNKB + is * 4096 + tid * 16,
              smem + LDS_ALO + is * 4096 + wv * 1024);
    }
    // ---- stage B: 8 floats of t -> bf16 hi/lo, swizzled ds_write
    {
      const float4 v0 = *(const float4*)(tsrc + ks * 32);
      const float4 v1 = *(const float4*)(tsrc + ks * 32 + 4);
      const float f[8] = {v0.x, v0.y, v0.z, v0.w, v1.x, v1.y, v1.z, v1.w};
      s16x8 hv, lv;
      #pragma unroll
      for (int q = 0; q < 8; ++q) {
        const unsigned short h = f2bf(f[q]);
        hv[q] = (short)h;
        lv[q] = (short)f2bf(f[q] - bf2f(h));
      }
      *(s16x8*)(smem + LDS_BHI + bbyte) = hv;
      *(s16x8*)(smem + LDS_BLO + bbyte) = lv;
    }
    __syncthreads();
    // ---- fragments + 3-pass MFMA (hi*hi + hi*lo + lo*hi)
    s16x8 Bh[4], Bl[4];
    #pragma unroll
    for (int j = 0; j < 4; ++j) {
      const int nn  = j * 16 + col;
      const int byo = ((nn * 64 + kg * 16) ^ ((nn & 7) << 4));
      Bh[j] = *(const s16x8*)(smem + LDS_BHI + byo);
      Bl[j] = *(const s16x8*)(smem + LDS_BLO + byo);
    }
    #pragma unroll
    for (int i = 0; i < 6; ++i) {
      const int m   = wv * 96 + i * 16 + col;
      const int byo = ((m * 64 + kg * 16) ^ ((m & 7) << 4));
      const s16x8 Ah = *(const s16x8*)(smem + LDS_AHI + byo);
      const s16x8 Al = *(const s16x8*)(smem + LDS_ALO + byo);
      #pragma unroll
      for (int j = 0; j < 4; ++j) {
        acc[i][j] = __builtin_amdgcn_mfma_f32_16x16x32_bf16(as_bf(Ah), as_bf(Bh[j]), acc[i][j], 0, 0, 0);
        acc[i][j] = __builtin_amdgcn_mfma_f32_16x16x32_bf16(as_bf(Ah), as_bf(Bl[j]), acc[i][j], 0, 0, 0);
        acc[i][j] = __builtin_amdgcn_mfma_f32_16x16x32_bf16(as_bf(Al), as_bf(Bh[j]), acc[i][j], 0, 0, 0);
      }
    }
  }

  // ---- epilogue: E = b*(dot - c[m]); column softmax over 384 rows; R^T out
  float* red  = (float*)(smem + LDS_RED);   // [4 waves][64 cols]
  float* red2 = red + 256;

  f32x4 c4[6];
  #pragma unroll
  for (int i = 0; i < 6; ++i)
    c4[i] = *(const f32x4*)(cbuf + wv * 96 + i * 16 + kg * 4);

  float colmax[4] = {-3.0e38f, -3.0e38f, -3.0e38f, -3.0e38f};
  #pragma unroll
  for (int i = 0; i < 6; ++i) {
    #pragma unroll
    for (int j = 0; j < 4; ++j) {
      acc[i][j] = (acc[i][j] - c4[i]) * b;   // padded rows: c=1e30 -> E ~ -1e30
      #pragma unroll
      for (int r = 0; r < 4; ++r) colmax[j] = fmaxf(colmax[j], acc[i][j][r]);
    }
  }
  #pragma unroll
  for (int j = 0; j < 4; ++j) {
    colmax[j] = fmaxf(colmax[j], __shfl_xor(colmax[j], 16));
    colmax[j] = fmaxf(colmax[j], __shfl_xor(colmax[j], 32));
  }
  if (lane < 16) {
    #pragma unroll
    for (int j = 0; j < 4; ++j) red[wv * 64 + j * 16 + lane] = colmax[j];
  }
  __syncthreads();

  float fullmax[4];
  float colsum[4] = {0.0f, 0.0f, 0.0f, 0.0f};
  #pragma unroll
  for (int j = 0; j < 4; ++j) {
    const int cc = j * 16 + col;
    fullmax[j] = fmaxf(fmaxf(red[cc], red[64 + cc]), fmaxf(red[128 + cc], red[192 + cc]));
  }
  #pragma unroll
  for (int i = 0; i < 6; ++i) {
    #pragma unroll
    for (int j = 0; j < 4; ++j) {
      #pragma unroll
      for (int r = 0; r < 4; ++r) {
        const float p = expf(acc[i][j][r] - fullmax[j]);  // pad rows -> exp(-huge) = 0
        acc[i][j][r] = p;
        colsum[j] += p;
      }
    }
  }
  #pragma unroll
  for (int j = 0; j < 4; ++j) {
    colsum[j] += __shfl_xor(colsum[j], 16);
    colsum[j] += __shfl_xor(colsum[j], 32);
  }
  if (lane < 16) {
    #pragma unroll
    for (int j = 0; j < 4; ++j) red2[wv * 64 + j * 16 + lane] = colsum[j];
  }
  __syncthreads();

  float s[4];
  #pragma unroll
  for (int j = 0; j < 4; ++j) {
    const int cc = j * 16 + col;
    s[j] = (red2[cc] + red2[64 + cc]) + (red2[128 + cc] + red2[192 + cc]);
  }

  // log-likelihood partial: wave 0, lanes 0..15 cover all 64 columns once
  float llp = 0.0f;
  if (lane < 16) {
    #pragma unroll
    for (int j = 0; j < 4; ++j) llp += logf(s[j]);
  }
  if (wv == 0) {
    #pragma unroll
    for (int mk = 1; mk < 64; mk <<= 1) llp += __shfl_xor(llp, mk);
    if (lane == 0) atomicAdd(llbuf, llp);
  }

  float inv[4];
  #pragma unroll
  for (int j = 0; j < 4; ++j) inv[j] = 1.0f / s[j];
  #pragma unroll
  for (int i = 0; i < 6; ++i) {
    #pragma unroll
    for (int j = 0; j < 4; ++j) acc[i][j] *= inv[j];
  }

  // ---- transpose via LDS (stride 18: write-conflict-free, reads 4-way) ----
  // FULLY unrolled over jj: acc must only ever be indexed by compile-time
  // constants (rule #20 — runtime index sends the whole array to scratch).
  float* Rt = (float*)smem;  // [384][18] floats = 27648 B, overlays dead A region
  #pragma unroll
  for (int jj = 0; jj < 4; ++jj) {
    __syncthreads();
    #pragma unroll
    for (int i = 0; i < 6; ++i) {
      const int mbase = wv * 96 + i * 16 + kg * 4;
      #pragma unroll
      for (int r = 0; r < 4; ++r) Rt[(mbase + r) * 18 + col] = acc[i][jj][r];
    }
    __syncthreads();
    #pragma unroll
    for (int c2l = 0; c2l < 4; ++c2l) {
      const int cc = wv * 4 + c2l;
      const size_t n = (size_t)(n0 + jj * 16 + cc);
      #pragma unroll
      for (int i2 = 0; i2 < 6; ++i2) {
        const int m = lane + 64 * i2;
        if (m < KNODES) out[1 + n * KNODES + m] = Rt[m * 18 + cc];
      }
    }
  }
}

// ---------------------------------------------------------------------------
__global__ void k_fin(const float* __restrict__ beta, const float* __restrict__ llbuf,
                      float* __restrict__ out) {
  const float b = beta[0];
  // -ll = -(256*log(b/2pi) - log(360) + (1/N)*sum log s)
  out[0] = -(256.0f * logf(b * (1.0f / 6.283185307179586f)) - logf(360.0f)
             + llbuf[0] * (1.0f / 131072.0f));
}

extern "C" void kernel_launch(void* const* d_in, const int* in_sizes, int n_in,
                              void* d_out, int out_size, void* d_ws, size_t ws_size,
                              hipStream_t stream) {
  const float* t    = (const float*)d_in[0];
  const float* W    = (const float*)d_in[1];
  const float* beta = (const float*)d_in[2];
  float* out = (float*)d_out;

  // ws layout: A_hi[393216 B] | A_lo[393216 B] | c[1536 B] | ll[4 B]  (~788 KB)
  unsigned short* ahi = (unsigned short*)d_ws;
  unsigned short* alo = (unsigned short*)((char*)d_ws + 393216);
  float* cbuf  = (float*)((char*)d_ws + 786432);
  float* llbuf = (float*)((char*)d_ws + 787968);

  hipLaunchKernelGGL(k_prep, dim3(MPAD), dim3(128), 0, stream, W, ahi, alo, cbuf, llbuf);
  hipLaunchKernelGGL(k_main, dim3(NBLK), dim3(256), 0, stream,
                     t, beta, ahi, alo, cbuf, out, llbuf);
  hipLaunchKernelGGL(k_fin, dim3(1), dim3(1), 0, stream, beta, llbuf, out);
}

// Round 4
// 534.789 us; speedup vs baseline: 3.2178x; 1.0547x over previous
//
#include <hip/hip_runtime.h>
#include <cstdint>
#include <cstddef>

// GTM forward: out[0] = -ll, out[1..] = R^T [N=131072][K=360]
//   E'_k(n) = b*(Y_k . t_n - 0.5*||Y_k||^2)   (||t||^2 shift cancels in softmax AND in log s)
//   R[:,n] = softmax_k(E'), ll_n = 256*log(b/2pi) + log(sum exp(E'-max)) - log 360
// GEMM via bf16 hi/lo split (3 MFMA passes) for fp32-grade accuracy on E.
//
// R3 -> R4: k_main was at the 2-phase structural ceiling (678 TF eff, MfmaUtil
// 29%, HBM 18%): stage->barrier drain fully exposed. Now: 8-wave/BN=128 block,
// double-buffered LDS (A 2x48K gload_lds + B 2x16K reg-staged), loads issued
// BEFORE the MFMA phase so the vmcnt(0)-before-barrier drains already-flown
// loads (T3-min), setprio around MFMA (T5, 2 waves/SIMD). k_prep parallelized
// (720 blocks, 1 elem/thread, atomicAdd'd ||Y||^2) - was latency-serial.

#define KNODES 360
#define MPAD   384
#define MRBF   145
#define DD     512
#define NTOT   131072
#define BN     128
#define NBLK   (NTOT / BN)     // 1024
#define NKS    (DD / 32)       // 16 K-steps of 32
#define CHUNKB (MPAD * 32 * 2) // 24576 bytes: one K-chunk of A (hi or lo) in bf16

// LDS map (bytes): A dbuf 2x49152 | B dbuf 2x16384 @98304 | red 4096 @131072
#define LDS_B   98304
#define LDS_RED 131072
#define LDS_TOT 135168

typedef float  f32x4  __attribute__((ext_vector_type(4)));
typedef short  s16x8  __attribute__((ext_vector_type(8)));
typedef __bf16 bf16x8 __attribute__((ext_vector_type(8)));

static __device__ __forceinline__ bf16x8 as_bf(s16x8 v) { return __builtin_bit_cast(bf16x8, v); }

// round-to-nearest-even fp32 -> bf16 (data has no NaN/Inf)
static __device__ __forceinline__ unsigned short f2bf(float x) {
  unsigned u = __float_as_uint(x);
  u += 0x7FFFu + ((u >> 16) & 1u);
  return (unsigned short)(u >> 16);
}
static __device__ __forceinline__ float bf2f(unsigned short h) {
  return __uint_as_float(((unsigned)h) << 16);
}

// async global->LDS, 16B per lane; LDS dest = wave-uniform base + lane*16
static __device__ __forceinline__ void gload16(const void* g, const char* l) {
  __builtin_amdgcn_global_load_lds(
      (const __attribute__((address_space(1))) void*)g,
      (__attribute__((address_space(3))) void*)l,
      16, 0, 0);
}

// ---------------------------------------------------------------------------
// init: zero the swizzled pad-row byte range of each A chunk (rows 360..383
// map exactly onto bytes [23040,24576) per chunk: the XOR set is closed),
// zero cbuf (atomicAdd target) and llbuf.
// ---------------------------------------------------------------------------
__global__ void k_init(unsigned short* __restrict__ ahi,
                       unsigned short* __restrict__ alo,
                       float* __restrict__ cbuf, float* __restrict__ llbuf) {
  const int c   = blockIdx.x;   // 16 chunks
  const int tid = threadIdx.x;  // 256
  unsigned* ph = (unsigned*)((char*)ahi + c * CHUNKB + 23040);
  unsigned* pl = (unsigned*)((char*)alo + c * CHUNKB + 23040);
  for (int o = tid; o < 384; o += 256) { ph[o] = 0u; pl[o] = 0u; }
  if (c == 0) {
    if (tid < MPAD) cbuf[tid] = 0.0f;
    if (tid == 0)   llbuf[0]  = 0.0f;
  }
}

// ---------------------------------------------------------------------------
// prep: Y = phi@W (one element per thread), store hi/lo bf16 pre-swizzled,
// accumulate 0.5*||Y_k||^2 into cbuf via per-block reduce + atomicAdd.
// grid (2, 360), 256 threads.
// ---------------------------------------------------------------------------
__global__ __launch_bounds__(256) void k_prep(const float* __restrict__ W,
                                              unsigned short* __restrict__ ahi,
                                              unsigned short* __restrict__ alo,
                                              float* __restrict__ cbuf) {
  const int k   = blockIdx.y;                    // latent row 0..359
  const int tid = threadIdx.x;                   // 0..255
  const int d   = blockIdx.x * 256 + tid;        // 0..511

  __shared__ float phi[MRBF];
  __shared__ float red[256];

  if (tid < MRBF) {
    float p = 1.0f;                              // bias column (m == 144)
    if (tid < MRBF - 1) {
      const float ca = -11.0f / 12.0f + (1.0f / 6.0f) * (float)(tid / 12);
      const float cb = -11.0f / 12.0f + (1.0f / 6.0f) * (float)(tid % 12);
      const float xa = -1.0f + (2.0f / 19.0f) * (float)(k / 18);
      const float xb = -1.0f + (2.0f / 17.0f) * (float)(k % 18);
      const float dx = xa - ca, dy = xb - cb;
      p = expf(-3.0f * (dx * dx + dy * dy));     // exp(-d2/(2*sigma)), sigma=1/6
    }
    phi[tid] = p;
  }
  __syncthreads();

  float y = 0.0f;
  for (int m = 0; m < MRBF; ++m) y = fmaf(phi[m], W[m * DD + d], y);

  const unsigned short h = f2bf(y);
  const unsigned short l = f2bf(y - bf2f(h));
  // swizzled byte offset inside chunk (d>>5): (row*64 + (d&31)*2) ^ ((row&7)<<4)
  const int idx = ((d >> 5) * CHUNKB + ((k * 64 + (d & 31) * 2) ^ ((k & 7) << 4))) >> 1;
  ahi[idx] = h;
  alo[idx] = l;

  red[tid] = y * y;
  __syncthreads();
  #pragma unroll
  for (int s = 128; s > 0; s >>= 1) {
    if (tid < s) red[tid] += red[tid + s];
    __syncthreads();
  }
  if (tid == 0) atomicAdd(&cbuf[k], 0.5f * red[0]);
}

// ---------------------------------------------------------------------------
// main: 8 waves (4 m-quarters x 2 n-halves), 384 rows x 128 cols per block,
// double-buffered pipeline, bf16x3 MFMA + fused softmax + transposed store.
// ---------------------------------------------------------------------------
__global__ __launch_bounds__(512, 2) void k_main(const float* __restrict__ t,
                                                 const float* __restrict__ beta,
                                                 const unsigned short* __restrict__ ahi,
                                                 const unsigned short* __restrict__ alo,
                                                 const float* __restrict__ cbuf,
                                                 float* __restrict__ out,
                                                 float* __restrict__ llbuf) {
  __shared__ __align__(16) char smem[LDS_TOT];
  const int tid  = threadIdx.x;
  const int lane = tid & 63;
  const int wv   = tid >> 6;     // 0..7
  const int wm   = wv & 3;       // m-quarter: rows [wm*96, wm*96+96)
  const int g    = wv >> 2;      // n-half:   cols [g*64, g*64+64)
  const int col  = lane & 15;
  const int kg   = lane >> 4;
  const int n0   = blockIdx.x * BN;
  const float b  = beta[0];

  f32x4 acc[6][4] = {};          // rows = wm*96+i*16+kg*4+r, col = g*64+j*16+col

  const float* tsrc = t + (size_t)(n0 + (tid >> 2)) * DD + (tid & 3) * 8;
  const int brow  = tid >> 2;    // 0..127 (B tile row = n index)
  const int bbyte = ((brow * 64 + (tid & 3) * 16) ^ ((brow & 7) << 4));

  // stage one A K-chunk (hi+lo, 48K) into buffer sbuf via global_load_lds
  auto stageA = [&](int sbuf, int ks) {
    const char* ah = (const char*)ahi + ks * CHUNKB + tid * 16;
    const char* al = (const char*)alo + ks * CHUNKB + tid * 16;
    char* da = smem + sbuf * 49152 + wv * 1024;
    #pragma unroll
    for (int is = 0; is < 3; ++is) {
      gload16(ah + is * 8192, da + is * 8192);
      gload16(al + is * 8192, da + 24576 + is * 8192);
    }
  };
  // convert 8 t-floats -> bf16 hi/lo and ds_write swizzled into buffer sbuf
  auto bconv = [&](int sbuf, float4 v0, float4 v1) {
    char* db = smem + LDS_B + sbuf * 16384;
    const float f[8] = {v0.x, v0.y, v0.z, v0.w, v1.x, v1.y, v1.z, v1.w};
    s16x8 hv, lv;
    #pragma unroll
    for (int q = 0; q < 8; ++q) {
      const unsigned short h = f2bf(f[q]);
      hv[q] = (short)h;
      lv[q] = (short)f2bf(f[q] - bf2f(h));
    }
    *(s16x8*)(db + bbyte) = hv;
    *(s16x8*)(db + 8192 + bbyte) = lv;
  };

  // ---- prologue: fill buffer 0
  stageA(0, 0);
  {
    const float4 v0 = *(const float4*)(tsrc);
    const float4 v1 = *(const float4*)(tsrc + 4);
    bconv(0, v0, v1);
  }
  __syncthreads();   // compiler drains vmcnt(0) lgkmcnt(0) here

  // ---- pipelined K-loop: issue ks+1 loads, compute ks, write B(ks+1), barrier
  for (int ks = 0; ks < NKS; ++ks) {
    const int cur  = ks & 1;
    const bool more = (ks + 1 < NKS);
    float4 p0, p1;
    if (more) {
      p0 = *(const float4*)(tsrc + (ks + 1) * 32);   // t prefetch (vmcnt-counted)
      p1 = *(const float4*)(tsrc + (ks + 1) * 32 + 4);
      stageA(cur ^ 1, ks + 1);                        // A prefetch -> other buffer
    }
    const char* Ab = smem + cur * 49152;
    const char* Bb = smem + LDS_B + cur * 16384;
    s16x8 Bh[4], Bl[4];
    #pragma unroll
    for (int j = 0; j < 4; ++j) {
      const int nn  = g * 64 + j * 16 + col;
      const int byo = ((nn * 64 + kg * 16) ^ ((nn & 7) << 4));
      Bh[j] = *(const s16x8*)(Bb + byo);
      Bl[j] = *(const s16x8*)(Bb + 8192 + byo);
    }
    __builtin_amdgcn_s_setprio(1);
    #pragma unroll
    for (int i = 0; i < 6; ++i) {
      const int m   = wm * 96 + i * 16 + col;
      const int byo = ((m * 64 + kg * 16) ^ ((m & 7) << 4));
      const s16x8 Ah = *(const s16x8*)(Ab + byo);
      const s16x8 Al = *(const s16x8*)(Ab + 24576 + byo);
      #pragma unroll
      for (int j = 0; j < 4; ++j) {
        acc[i][j] = __builtin_amdgcn_mfma_f32_16x16x32_bf16(as_bf(Ah), as_bf(Bh[j]), acc[i][j], 0, 0, 0);
        acc[i][j] = __builtin_amdgcn_mfma_f32_16x16x32_bf16(as_bf(Ah), as_bf(Bl[j]), acc[i][j], 0, 0, 0);
        acc[i][j] = __builtin_amdgcn_mfma_f32_16x16x32_bf16(as_bf(Al), as_bf(Bh[j]), acc[i][j], 0, 0, 0);
      }
    }
    __builtin_amdgcn_s_setprio(0);
    if (more) bconv(cur ^ 1, p0, p1);   // compiler waits counted vmcnt for p0/p1
    __syncthreads();                    // vmcnt(0) drain: A loads flew under MFMA
  }

  // ---- epilogue: E = b*(dot - c); per-group column softmax over 384 rows
  float* red  = (float*)(smem + LDS_RED + g * 2048);  // [4 wm][64 cols]
  float* red2 = red + 256;

  float carr[6][4];
  #pragma unroll
  for (int i = 0; i < 6; ++i) {
    #pragma unroll
    for (int r = 0; r < 4; ++r) {
      const int row = wm * 96 + i * 16 + kg * 4 + r;
      carr[i][r] = (row < KNODES) ? cbuf[row] : 1.0e30f;  // pad rows -> E ~ -1e30
    }
  }

  float colmax[4] = {-3.0e38f, -3.0e38f, -3.0e38f, -3.0e38f};
  #pragma unroll
  for (int i = 0; i < 6; ++i) {
    #pragma unroll
    for (int j = 0; j < 4; ++j) {
      #pragma unroll
      for (int r = 0; r < 4; ++r) {
        acc[i][j][r] = (acc[i][j][r] - carr[i][r]) * b;
        colmax[j] = fmaxf(colmax[j], acc[i][j][r]);
      }
    }
  }
  #pragma unroll
  for (int j = 0; j < 4; ++j) {
    colmax[j] = fmaxf(colmax[j], __shfl_xor(colmax[j], 16));
    colmax[j] = fmaxf(colmax[j], __shfl_xor(colmax[j], 32));
  }
  if (lane < 16) {
    #pragma unroll
    for (int j = 0; j < 4; ++j) red[wm * 64 + j * 16 + lane] = colmax[j];
  }
  __syncthreads();

  float fullmax[4];
  float colsum[4] = {0.0f, 0.0f, 0.0f, 0.0f};
  #pragma unroll
  for (int j = 0; j < 4; ++j) {
    const int cc = j * 16 + col;
    fullmax[j] = fmaxf(fmaxf(red[cc], red[64 + cc]), fmaxf(red[128 + cc], red[192 + cc]));
  }
  #pragma unroll
  for (int i = 0; i < 6; ++i) {
    #pragma unroll
    for (int j = 0; j < 4; ++j) {
      #pragma unroll
      for (int r = 0; r < 4; ++r) {
        const float p = expf(acc[i][j][r] - fullmax[j]);
        acc[i][j][r] = p;
        colsum[j] += p;
      }
    }
  }
  #pragma unroll
  for (int j = 0; j < 4; ++j) {
    colsum[j] += __shfl_xor(colsum[j], 16);
    colsum[j] += __shfl_xor(colsum[j], 32);
  }
  if (lane < 16) {
    #pragma unroll
    for (int j = 0; j < 4; ++j) red2[wm * 64 + j * 16 + lane] = colsum[j];
  }
  __syncthreads();

  float s[4];
  #pragma unroll
  for (int j = 0; j < 4; ++j) {
    const int cc = j * 16 + col;
    s[j] = (red2[cc] + red2[64 + cc]) + (red2[128 + cc] + red2[192 + cc]);
  }

  // log-likelihood partial: per group, wave wm==0, lanes 0..15 cover 64 cols
  float llp = 0.0f;
  if (lane < 16) {
    #pragma unroll
    for (int j = 0; j < 4; ++j) llp += logf(s[j]);
  }
  if (wm == 0) {
    #pragma unroll
    for (int mk = 1; mk < 64; mk <<= 1) llp += __shfl_xor(llp, mk);
    if (lane == 0) atomicAdd(llbuf, llp);
  }

  float inv[4];
  #pragma unroll
  for (int j = 0; j < 4; ++j) inv[j] = 1.0f / s[j];
  #pragma unroll
  for (int i = 0; i < 6; ++i) {
    #pragma unroll
    for (int j = 0; j < 4; ++j) acc[i][j] *= inv[j];
  }

  // ---- transpose via LDS (stride 18) + coalesced column stores.
  // Per-group Rt buffers overlay the (dead) A double-buffer region.
  float* Rt = (float*)(smem + g * 32768);  // [384][18] f32 = 27648 B
  #pragma unroll
  for (int jj = 0; jj < 4; ++jj) {
    __syncthreads();
    #pragma unroll
    for (int i = 0; i < 6; ++i) {
      const int mbase = wm * 96 + i * 16 + kg * 4;
      #pragma unroll
      for (int r = 0; r < 4; ++r) Rt[(mbase + r) * 18 + col] = acc[i][jj][r];
    }
    __syncthreads();
    #pragma unroll
    for (int c2l = 0; c2l < 4; ++c2l) {
      const int cc = wm * 4 + c2l;
      const size_t n = (size_t)(n0 + g * 64 + jj * 16 + cc);
      #pragma unroll
      for (int i2 = 0; i2 < 6; ++i2) {
        const int m = lane + 64 * i2;
        if (m < KNODES) out[1 + n * KNODES + m] = Rt[m * 18 + cc];
      }
    }
  }
}

// ---------------------------------------------------------------------------
__global__ void k_fin(const float* __restrict__ beta, const float* __restrict__ llbuf,
                      float* __restrict__ out) {
  const float b = beta[0];
  // -ll = -(256*log(b/2pi) - log(360) + (1/N)*sum log s)
  out[0] = -(256.0f * logf(b * (1.0f / 6.283185307179586f)) - logf(360.0f)
             + llbuf[0] * (1.0f / 131072.0f));
}

extern "C" void kernel_launch(void* const* d_in, const int* in_sizes, int n_in,
                              void* d_out, int out_size, void* d_ws, size_t ws_size,
                              hipStream_t stream) {
  const float* t    = (const float*)d_in[0];
  const float* W    = (const float*)d_in[1];
  const float* beta = (const float*)d_in[2];
  float* out = (float*)d_out;

  // ws layout: A_hi[393216 B] | A_lo[393216 B] | c[1536 B] | ll[4 B]  (~788 KB)
  unsigned short* ahi = (unsigned short*)d_ws;
  unsigned short* alo = (unsigned short*)((char*)d_ws + 393216);
  float* cbuf  = (float*)((char*)d_ws + 786432);
  float* llbuf = (float*)((char*)d_ws + 787968);

  hipLaunchKernelGGL(k_init, dim3(16), dim3(256), 0, stream, ahi, alo, cbuf, llbuf);
  hipLaunchKernelGGL(k_prep, dim3(2, KNODES), dim3(256), 0, stream, W, ahi, alo, cbuf);
  hipLaunchKernelGGL(k_main, dim3(NBLK), dim3(512), 0, stream,
                     t, beta, ahi, alo, cbuf, out, llbuf);
  hipLaunchKernelGGL(k_fin, dim3(1), dim3(1), 0, stream, beta, llbuf, out);
}